// Round 4
// baseline (214.394 us; speedup 1.0000x reference)
//
#include <hip/hip_runtime.h>
#include <math.h>

#define BB 4
#define CC 256
#define NN 4096
#define DQ 32
#define LOG2E 1.44269504f

typedef _Float16 half8 __attribute__((ext_vector_type(8)));
typedef _Float16 half4 __attribute__((ext_vector_type(4)));
typedef float float4v __attribute__((ext_vector_type(4)));

// ---------------- prep: W -> f16 (log2e folded into Wq/bq) ----------------
__global__ __launch_bounds__(64) void prep_kernel(
    const float* __restrict__ Wq, const float* __restrict__ bq,
    const float* __restrict__ Wk, const float* __restrict__ bk,
    const float* __restrict__ Wv, const float* __restrict__ bv,
    _Float16* __restrict__ Wh, float* __restrict__ bh)
{
    int o = blockIdx.x, t = threadIdx.x;
    const float* src; float scale = 1.0f, bias;
    if (o < DQ)            { src = Wq + o * CC;        scale = LOG2E; bias = bq[o] * LOG2E; }
    else if (o < 2 * DQ)   { src = Wk + (o - DQ) * CC;                bias = bk[o - DQ]; }
    else                   { src = Wv + (o - 2 * DQ) * CC;            bias = bv[o - 2 * DQ]; }
    float4 v = *(const float4*)(src + t * 4);
    half4 h = { (_Float16)(v.x * scale), (_Float16)(v.y * scale),
                (_Float16)(v.z * scale), (_Float16)(v.w * scale) };
    *(half4*)(Wh + o * CC + t * 4) = h;
    if (t == 0) bh[o] = bias;
}

// ---------------- proj: MFMA GEMM, all 320 outputs x 32-pixel tile ----------------
__global__ __launch_bounds__(256) void proj_kernel(
    const float* __restrict__ x, const _Float16* __restrict__ Wh,
    const float* __restrict__ bh,
    _Float16* __restrict__ Qt, _Float16* __restrict__ Kt,
    _Float16* __restrict__ Vh)
{
    __shared__ _Float16 xl[32 * 256];
    __shared__ _Float16 os_qk[32 * 72];
    __shared__ _Float16 os_v[256 * 40];

    const int tid = threadIdx.x;
    const int lane = tid & 63, w = tid >> 6;
    const int i16 = lane & 15, q = lane >> 4;
    const int n0 = blockIdx.x * 32, b = blockIdx.y;

    const float* xb = x + (size_t)b * CC * NN + n0;
    #pragma unroll
    for (int u = 0; u < 8; ++u) {
        int idx = u * 256 + tid;
        int c = idx >> 3, n4 = idx & 7;
        float4 v = *(const float4*)(xb + (size_t)c * NN + n4 * 4);
        int chunk = c >> 3, cl = c & 7;
        float vv[4] = {v.x, v.y, v.z, v.w};
        #pragma unroll
        for (int e = 0; e < 4; ++e) {
            int n = n4 * 4 + e;
            xl[n * 256 + ((chunk ^ n) * 8) + cl] = (_Float16)vv[e];
        }
    }

    float4v acc[5][2];
    const int obase = 80 * w;
    #pragma unroll
    for (int ot = 0; ot < 5; ++ot) {
        float4 b4 = *(const float4*)(bh + obase + 16 * ot + 4 * q);
        #pragma unroll
        for (int nt = 0; nt < 2; ++nt)
            acc[ot][nt] = (float4v){b4.x, b4.y, b4.z, b4.w};
    }
    __syncthreads();

    #pragma unroll
    for (int k = 0; k < 8; ++k) {
        half8 af[5], bf[2];
        #pragma unroll
        for (int ot = 0; ot < 5; ++ot)
            af[ot] = *(const half8*)(Wh + (size_t)(obase + 16 * ot + i16) * CC + k * 32 + 8 * q);
        #pragma unroll
        for (int nt = 0; nt < 2; ++nt) {
            int n = 16 * nt + i16;
            bf[nt] = *(const half8*)&xl[n * 256 + (((4 * k + q) ^ n) * 8)];
        }
        #pragma unroll
        for (int ot = 0; ot < 5; ++ot)
            #pragma unroll
            for (int nt = 0; nt < 2; ++nt)
                acc[ot][nt] = __builtin_amdgcn_mfma_f32_16x16x32_f16(af[ot], bf[nt], acc[ot][nt], 0, 0, 0);
    }

    #pragma unroll
    for (int ot = 0; ot < 5; ++ot) {
        int og = obase + 16 * ot;
        #pragma unroll
        for (int nt = 0; nt < 2; ++nt) {
            int n = 16 * nt + i16;
            if (og < 64) {
                half4 hv = { (_Float16)acc[ot][nt][0], (_Float16)acc[ot][nt][1],
                             (_Float16)acc[ot][nt][2], (_Float16)acc[ot][nt][3] };
                *(half4*)&os_qk[n * 72 + og + 4 * q] = hv;
            } else {
                int cb = og - 64 + 4 * q;
                #pragma unroll
                for (int r = 0; r < 4; ++r)
                    os_v[(cb + r) * 40 + n] = (_Float16)acc[ot][nt][r];
            }
        }
    }
    __syncthreads();

    _Float16* Qtb = Qt + (size_t)b * NN * DQ;
    _Float16* Ktb = Kt + (size_t)b * NN * DQ;
    {
        int n = tid >> 3, p = tid & 7;
        half8 hv = *(const half8*)&os_qk[n * 72 + 8 * p];
        if (p < 4) *(half8*)(Qtb + (size_t)(n0 + n) * DQ + 8 * p) = hv;
        else       *(half8*)(Ktb + (size_t)(n0 + n) * DQ + 8 * (p - 4)) = hv;
    }
    _Float16* Vb = Vh + (size_t)b * CC * NN;
    #pragma unroll
    for (int u = 0; u < 4; ++u) {
        int c = u * 64 + (tid >> 2), p = tid & 3;
        half8 hv = *(const half8*)&os_v[c * 40 + 8 * p];
        *(half8*)(Vb + (size_t)c * NN + n0 + 8 * p) = hv;
    }
}

// ---------------- attn: fused stats (pass A) + pipelined PV (pass B) ----------------
// Pass A (barrier-free): wave w streams keys [1024w,1024w+1024), K loaded
// directly as A-fragments (2-deep prefetch), per-query m = max, l = sum
// exp2(s) reference-0 (f32-safe: < 2^56). Combine: shfl over q-quads, then
// 2KB LDS exchange across waves + 1 barrier.
// Pass B: identical to round-3 verified 1-barrier software-pipelined loop.
__global__ __launch_bounds__(256) void attn_kernel(
    const float* __restrict__ x,
    const _Float16* __restrict__ Qt, const _Float16* __restrict__ Kt,
    const _Float16* __restrict__ Vh,
    float* __restrict__ out)
{
    __shared__ _Float16 k_lds[2][64 * 32];    // [j][d], d-chunk ^= (j&3)
    __shared__ _Float16 v_lds[3][128 * 64];   // [c][j], j-chunk ^= (c&7)
    __shared__ _Float16 ps[2][64 * 72];       // P': [i][j + pad]
    __shared__ float    st_m[4][64];          // pass-A exchange
    __shared__ float    st_l[4][64];

    const int tid = threadIdx.x;
    const int w = tid >> 6, lane = tid & 63;
    const int i16 = lane & 15, q = lane >> 4;
    const int i0 = blockIdx.x * 64, cs = blockIdx.y, b = blockIdx.z;
    const int c0 = cs * 128;

    const _Float16* Ktb = Kt + (size_t)b * NN * DQ;
    const _Float16* Vb  = Vh + (size_t)b * CC * NN + (size_t)c0 * NN;

    half8 qb[4];
    {
        const _Float16* Qtb = Qt + (size_t)b * NN * DQ;
        #pragma unroll
        for (int it = 0; it < 4; ++it)
            qb[it] = *(const half8*)(Qtb + (size_t)(i0 + 16 * it + i16) * DQ + 8 * q);
    }

    // ---- pass A: stats over this wave's key quarter ----
    float mA[4] = {-INFINITY, -INFINITY, -INFINITY, -INFINITY};
    float lA[4] = {0.f, 0.f, 0.f, 0.f};
    {
        const _Float16* kq = Ktb + (size_t)(1024 * w) * DQ;
        half8 kfr0 = *(const half8*)(kq + (size_t)i16 * DQ + 8 * q);
        half8 kfr1 = *(const half8*)(kq + (size_t)(16 + i16) * DQ + 8 * q);
        for (int t = 0; t < 64; t += 2) {
            {
                half8 ka = kfr0;
                if (t + 2 < 64)
                    kfr0 = *(const half8*)(kq + (size_t)(16 * (t + 2) + i16) * DQ + 8 * q);
                #pragma unroll
                for (int it = 0; it < 4; ++it) {
                    float4v z = {0.f, 0.f, 0.f, 0.f};
                    float4v s = __builtin_amdgcn_mfma_f32_16x16x32_f16(ka, qb[it], z, 0, 0, 0);
                    mA[it] = fmaxf(mA[it], fmaxf(fmaxf(s[0], s[1]), fmaxf(s[2], s[3])));
                    lA[it] += (exp2f(s[0]) + exp2f(s[1])) + (exp2f(s[2]) + exp2f(s[3]));
                }
            }
            {
                half8 ka = kfr1;
                if (t + 3 < 64)
                    kfr1 = *(const half8*)(kq + (size_t)(16 * (t + 3) + i16) * DQ + 8 * q);
                #pragma unroll
                for (int it = 0; it < 4; ++it) {
                    float4v z = {0.f, 0.f, 0.f, 0.f};
                    float4v s = __builtin_amdgcn_mfma_f32_16x16x32_f16(ka, qb[it], z, 0, 0, 0);
                    mA[it] = fmaxf(mA[it], fmaxf(fmaxf(s[0], s[1]), fmaxf(s[2], s[3])));
                    lA[it] += (exp2f(s[0]) + exp2f(s[1])) + (exp2f(s[2]) + exp2f(s[3]));
                }
            }
        }
        #pragma unroll
        for (int it = 0; it < 4; ++it) {
            lA[it] += __shfl_xor(lA[it], 16, 64);
            lA[it] += __shfl_xor(lA[it], 32, 64);
            mA[it] = fmaxf(mA[it], __shfl_xor(mA[it], 16, 64));
            mA[it] = fmaxf(mA[it], __shfl_xor(mA[it], 32, 64));
        }
        if (q == 0) {
            #pragma unroll
            for (int it = 0; it < 4; ++it) {
                st_m[w][16 * it + i16] = mA[it];
                st_l[w][16 * it + i16] = lA[it];
            }
        }
    }
    __syncthreads();

    float m2v[4], linv[4];
    #pragma unroll
    for (int it = 0; it < 4; ++it) {
        int qrow = 16 * it + i16;
        float mm = fmaxf(fmaxf(st_m[0][qrow], st_m[1][qrow]),
                         fmaxf(st_m[2][qrow], st_m[3][qrow]));
        float ll = (st_l[0][qrow] + st_l[1][qrow]) + (st_l[2][qrow] + st_l[3][qrow]);
        m2v[it] = mm;
        linv[it] = exp2f(mm) / ll;   // 1 / sum_j exp2(s_j - mm)
    }

    // ---- pass B: software-pipelined PV loop (round-3 verified) ----
    float4v O[2][4];
    #pragma unroll
    for (int ct = 0; ct < 2; ++ct)
        #pragma unroll
        for (int it = 0; it < 4; ++it)
            O[ct][it] = (float4v){0.f, 0.f, 0.f, 0.f};

    const int jK = tid >> 2, dgK = tid & 3;      // K: 1 half8/thread
    const int cbV = tid >> 3, jgV = tid & 7;     // V: 4 half8/thread
    const int kaddr = jK * 32 + ((dgK ^ (jK & 3)) * 8);
    int vaddr[4];
    #pragma unroll
    for (int u = 0; u < 4; ++u) {
        int c = u * 32 + cbV;
        vaddr[u] = c * 64 + ((jgV ^ (c & 7)) * 8);
    }

    half8 kv, vv[4];
    kv = *(const half8*)(Ktb + (size_t)jK * DQ + 8 * dgK);
    #pragma unroll
    for (int u = 0; u < 4; ++u)
        vv[u] = *(const half8*)(Vb + (size_t)(u * 32 + cbV) * NN + 8 * jgV);
    *(half8*)&k_lds[0][kaddr] = kv;
    #pragma unroll
    for (int u = 0; u < 4; ++u)
        *(half8*)&v_lds[0][vaddr[u]] = vv[u];
    kv = *(const half8*)(Ktb + (size_t)(64 + jK) * DQ + 8 * dgK);
    #pragma unroll
    for (int u = 0; u < 4; ++u)
        vv[u] = *(const half8*)(Vb + (size_t)(u * 32 + cbV) * NN + 64 + 8 * jgV);

    for (int t = 0; t <= 64; ++t) {
        __syncthreads();
        // stage tile t+1 from regs (loaded at iter t-1)
        if (t < 63) {
            *(half8*)&k_lds[(t + 1) & 1][kaddr] = kv;
            const int vn = (t + 1) % 3;
            #pragma unroll
            for (int u = 0; u < 4; ++u)
                *(half8*)&v_lds[vn][vaddr[u]] = vv[u];
        }
        // issue prefetch of tile t+2 (drained by next barrier; covers S+PV)
        if (t < 62) {
            int jn = (t + 2) * 64;
            kv = *(const half8*)(Ktb + (size_t)(jn + jK) * DQ + 8 * dgK);
            #pragma unroll
            for (int u = 0; u < 4; ++u)
                vv[u] = *(const half8*)(Vb + (size_t)(u * 32 + cbV) * NN + jn + 8 * jgV);
        }
        // PV(t-1): inputs were completed before this iter's barrier
        if (t > 0) {
            const _Float16* psp = ps[(t - 1) & 1];
            const _Float16* vp  = v_lds[(t - 1) % 3];
            half8 pb[2][4];
            #pragma unroll
            for (int ks = 0; ks < 2; ++ks)
                #pragma unroll
                for (int it = 0; it < 4; ++it)
                    pb[ks][it] = *(const half8*)&psp[(16 * it + i16) * 72 + 32 * ks + 8 * q];
            __builtin_amdgcn_s_setprio(1);
            #pragma unroll
            for (int ct = 0; ct < 2; ++ct) {
                int c = 32 * w + 16 * ct + i16;
                #pragma unroll
                for (int ks = 0; ks < 2; ++ks) {
                    int g = 4 * ks + q;
                    half8 va = *(const half8*)&vp[c * 64 + ((g ^ (c & 7)) * 8)];
                    #pragma unroll
                    for (int it = 0; it < 4; ++it)
                        O[ct][it] = __builtin_amdgcn_mfma_f32_16x16x32_f16(va, pb[ks][it], O[ct][it], 0, 0, 0);
                }
            }
            __builtin_amdgcn_s_setprio(0);
        }
        // S(t) -> ps[t&1]
        if (t < 64) {
            int j = 16 * w + i16;
            half8 ka = *(const half8*)&k_lds[t & 1][j * 32 + ((q ^ (j & 3)) * 8)];
            _Float16* psc = ps[t & 1];
            #pragma unroll
            for (int it = 0; it < 4; ++it) {
                float4v z = {0.f, 0.f, 0.f, 0.f};
                float4v s = __builtin_amdgcn_mfma_f32_16x16x32_f16(ka, qb[it], z, 0, 0, 0);
                half4 hv = { (_Float16)exp2f(s[0] - m2v[it]),
                             (_Float16)exp2f(s[1] - m2v[it]),
                             (_Float16)exp2f(s[2] - m2v[it]),
                             (_Float16)exp2f(s[3] - m2v[it]) };
                *(half4*)&psc[(16 * it + i16) * 72 + 16 * w + 4 * q] = hv;
            }
        }
    }

    // epilogue: O * (1/l) + residual
    const float* xb = x + (size_t)b * CC * NN;
    float* ob = out + (size_t)b * CC * NN;
    #pragma unroll
    for (int ct = 0; ct < 2; ++ct)
        #pragma unroll
        for (int it = 0; it < 4; ++it)
            #pragma unroll
            for (int r = 0; r < 4; ++r) {
                int c = c0 + 32 * w + 16 * ct + 4 * q + r;
                size_t idx = (size_t)c * NN + i0 + 16 * it + i16;
                ob[idx] = xb[idx] + O[ct][it][r] * linv[it];
            }
}

extern "C" void kernel_launch(void* const* d_in, const int* in_sizes, int n_in,
                              void* d_out, int out_size, void* d_ws, size_t ws_size,
                              hipStream_t stream) {
    const float* x  = (const float*)d_in[0];
    const float* Wq = (const float*)d_in[1];
    const float* bq = (const float*)d_in[2];
    const float* Wk = (const float*)d_in[3];
    const float* bk = (const float*)d_in[4];
    const float* Wv = (const float*)d_in[5];
    const float* bv = (const float*)d_in[6];
    float* out = (float*)d_out;

    char* ws = (char*)d_ws;
    _Float16* Wh = (_Float16*)(ws);                 // 320*256*2 = 163840
    float*    bh = (float*)(ws + 163840);           // 1280
    _Float16* Qt = (_Float16*)(ws + 262144);        // 4*4096*32*2 = 1 MB
    _Float16* Kt = (_Float16*)(ws + 1310720);       // 1 MB
    _Float16* Vh = (_Float16*)(ws + 2359296);       // 4*256*4096*2 = 8 MB

    prep_kernel<<<dim3(320), 64, 0, stream>>>(Wq, bq, Wk, bk, Wv, bv, Wh, bh);
    proj_kernel<<<dim3(NN / 32, BB), 256, 0, stream>>>(x, Wh, bh, Qt, Kt, Vh);
    attn_kernel<<<dim3(NN / 64, 2, BB), 256, 0, stream>>>(x, Qt, Kt, Vh, out);
}

// Round 5
// 193.428 us; speedup vs baseline: 1.1084x; 1.1084x over previous
//
#include <hip/hip_runtime.h>
#include <math.h>

#define BB 4
#define CC 256
#define NN 4096
#define DQ 32
#define LOG2E 1.44269504f

typedef _Float16 half8 __attribute__((ext_vector_type(8)));
typedef _Float16 half4 __attribute__((ext_vector_type(4)));
typedef float float4v __attribute__((ext_vector_type(4)));

// ---------------- prep: W -> f16 (log2e folded into Wq/bq) ----------------
__global__ __launch_bounds__(64) void prep_kernel(
    const float* __restrict__ Wq, const float* __restrict__ bq,
    const float* __restrict__ Wk, const float* __restrict__ bk,
    const float* __restrict__ Wv, const float* __restrict__ bv,
    _Float16* __restrict__ Wh, float* __restrict__ bh)
{
    int o = blockIdx.x, t = threadIdx.x;
    const float* src; float scale = 1.0f, bias;
    if (o < DQ)            { src = Wq + o * CC;        scale = LOG2E; bias = bq[o] * LOG2E; }
    else if (o < 2 * DQ)   { src = Wk + (o - DQ) * CC;                bias = bk[o - DQ]; }
    else                   { src = Wv + (o - 2 * DQ) * CC;            bias = bv[o - 2 * DQ]; }
    float4 v = *(const float4*)(src + t * 4);
    half4 h = { (_Float16)(v.x * scale), (_Float16)(v.y * scale),
                (_Float16)(v.z * scale), (_Float16)(v.w * scale) };
    *(half4*)(Wh + o * CC + t * 4) = h;
    if (t == 0) bh[o] = bias;
}

// ---------------- proj: MFMA GEMM, all 320 outputs x 32-pixel tile ----------------
__global__ __launch_bounds__(256) void proj_kernel(
    const float* __restrict__ x, const _Float16* __restrict__ Wh,
    const float* __restrict__ bh,
    _Float16* __restrict__ Qt, _Float16* __restrict__ Kt,
    _Float16* __restrict__ Vh)
{
    __shared__ _Float16 xl[32 * 256];
    __shared__ _Float16 os_qk[32 * 72];
    __shared__ _Float16 os_v[256 * 40];

    const int tid = threadIdx.x;
    const int lane = tid & 63, w = tid >> 6;
    const int i16 = lane & 15, q = lane >> 4;
    const int n0 = blockIdx.x * 32, b = blockIdx.y;

    const float* xb = x + (size_t)b * CC * NN + n0;
    #pragma unroll
    for (int u = 0; u < 8; ++u) {
        int idx = u * 256 + tid;
        int c = idx >> 3, n4 = idx & 7;
        float4 v = *(const float4*)(xb + (size_t)c * NN + n4 * 4);
        int chunk = c >> 3, cl = c & 7;
        float vv[4] = {v.x, v.y, v.z, v.w};
        #pragma unroll
        for (int e = 0; e < 4; ++e) {
            int n = n4 * 4 + e;
            xl[n * 256 + ((chunk ^ n) * 8) + cl] = (_Float16)vv[e];
        }
    }

    float4v acc[5][2];
    const int obase = 80 * w;
    #pragma unroll
    for (int ot = 0; ot < 5; ++ot) {
        float4 b4 = *(const float4*)(bh + obase + 16 * ot + 4 * q);
        #pragma unroll
        for (int nt = 0; nt < 2; ++nt)
            acc[ot][nt] = (float4v){b4.x, b4.y, b4.z, b4.w};
    }
    __syncthreads();

    #pragma unroll
    for (int k = 0; k < 8; ++k) {
        half8 af[5], bf[2];
        #pragma unroll
        for (int ot = 0; ot < 5; ++ot)
            af[ot] = *(const half8*)(Wh + (size_t)(obase + 16 * ot + i16) * CC + k * 32 + 8 * q);
        #pragma unroll
        for (int nt = 0; nt < 2; ++nt) {
            int n = 16 * nt + i16;
            bf[nt] = *(const half8*)&xl[n * 256 + (((4 * k + q) ^ n) * 8)];
        }
        #pragma unroll
        for (int ot = 0; ot < 5; ++ot)
            #pragma unroll
            for (int nt = 0; nt < 2; ++nt)
                acc[ot][nt] = __builtin_amdgcn_mfma_f32_16x16x32_f16(af[ot], bf[nt], acc[ot][nt], 0, 0, 0);
    }

    #pragma unroll
    for (int ot = 0; ot < 5; ++ot) {
        int og = obase + 16 * ot;
        #pragma unroll
        for (int nt = 0; nt < 2; ++nt) {
            int n = 16 * nt + i16;
            if (og < 64) {
                half4 hv = { (_Float16)acc[ot][nt][0], (_Float16)acc[ot][nt][1],
                             (_Float16)acc[ot][nt][2], (_Float16)acc[ot][nt][3] };
                *(half4*)&os_qk[n * 72 + og + 4 * q] = hv;
            } else {
                int cb = og - 64 + 4 * q;
                #pragma unroll
                for (int r = 0; r < 4; ++r)
                    os_v[(cb + r) * 40 + n] = (_Float16)acc[ot][nt][r];
            }
        }
    }
    __syncthreads();

    _Float16* Qtb = Qt + (size_t)b * NN * DQ;
    _Float16* Ktb = Kt + (size_t)b * NN * DQ;
    {
        int n = tid >> 3, p = tid & 7;
        half8 hv = *(const half8*)&os_qk[n * 72 + 8 * p];
        if (p < 4) *(half8*)(Qtb + (size_t)(n0 + n) * DQ + 8 * p) = hv;
        else       *(half8*)(Ktb + (size_t)(n0 + n) * DQ + 8 * (p - 4)) = hv;
    }
    _Float16* Vb = Vh + (size_t)b * CC * NN;
    #pragma unroll
    for (int u = 0; u < 4; ++u) {
        int c = u * 64 + (tid >> 2), p = tid & 3;
        half8 hv = *(const half8*)&os_v[c * 40 + 8 * p];
        *(half8*)(Vb + (size_t)c * NN + n0 + 8 * p) = hv;
    }
}

// ---------------- attn: max-only prepass + pipelined PV with inline l ----------------
// Pass M (barrier-free, NO exp2): wave w streams keys [1024w,1024w+1024) as
// direct A-fragments, per-query running max only (4 MFMA + 16 fmax per tile).
// Combine: shfl over q-quads + 1KB LDS exchange + 1 barrier -> m2v[4].
// Pass B: round-3 verified 1-barrier pipelined loop; l accumulated from the
// f32 P' values already computed there (each (query,key) P' is produced by
// exactly one lane -> lB[it] += p0+p1+p2+p3; reduce at end). linv applied
// in epilogue.
__global__ __launch_bounds__(256) void attn_kernel(
    const float* __restrict__ x,
    const _Float16* __restrict__ Qt, const _Float16* __restrict__ Kt,
    const _Float16* __restrict__ Vh,
    float* __restrict__ out)
{
    __shared__ _Float16 k_lds[2][64 * 32];    // [j][d], d-chunk ^= (j&3)
    __shared__ _Float16 v_lds[3][128 * 64];   // [c][j], j-chunk ^= (c&7)
    __shared__ _Float16 ps[2][64 * 72];       // P': [i][j + pad]
    __shared__ float    stx[4][64];           // cross-wave exchange (m, then l)

    const int tid = threadIdx.x;
    const int w = tid >> 6, lane = tid & 63;
    const int i16 = lane & 15, q = lane >> 4;
    const int i0 = blockIdx.x * 64, cs = blockIdx.y, b = blockIdx.z;
    const int c0 = cs * 128;

    const _Float16* Ktb = Kt + (size_t)b * NN * DQ;
    const _Float16* Vb  = Vh + (size_t)b * CC * NN + (size_t)c0 * NN;

    half8 qb[4];
    {
        const _Float16* Qtb = Qt + (size_t)b * NN * DQ;
        #pragma unroll
        for (int it = 0; it < 4; ++it)
            qb[it] = *(const half8*)(Qtb + (size_t)(i0 + 16 * it + i16) * DQ + 8 * q);
    }

    // ---- pass M: per-query max over this wave's key quarter (no exp2) ----
    float mA[4] = {-INFINITY, -INFINITY, -INFINITY, -INFINITY};
    {
        const _Float16* kq = Ktb + (size_t)(1024 * w) * DQ;
        half8 kf0 = *(const half8*)(kq + (size_t)i16 * DQ + 8 * q);
        half8 kf1 = *(const half8*)(kq + (size_t)(16 + i16) * DQ + 8 * q);
        for (int t = 0; t < 64; t += 2) {
            {
                half8 ka = kf0;
                if (t + 2 < 64)
                    kf0 = *(const half8*)(kq + (size_t)(16 * (t + 2) + i16) * DQ + 8 * q);
                #pragma unroll
                for (int it = 0; it < 4; ++it) {
                    float4v z = {0.f, 0.f, 0.f, 0.f};
                    float4v s = __builtin_amdgcn_mfma_f32_16x16x32_f16(ka, qb[it], z, 0, 0, 0);
                    mA[it] = fmaxf(mA[it], fmaxf(fmaxf(s[0], s[1]), fmaxf(s[2], s[3])));
                }
            }
            {
                half8 ka = kf1;
                if (t + 3 < 64)
                    kf1 = *(const half8*)(kq + (size_t)(16 * (t + 3) + i16) * DQ + 8 * q);
                #pragma unroll
                for (int it = 0; it < 4; ++it) {
                    float4v z = {0.f, 0.f, 0.f, 0.f};
                    float4v s = __builtin_amdgcn_mfma_f32_16x16x32_f16(ka, qb[it], z, 0, 0, 0);
                    mA[it] = fmaxf(mA[it], fmaxf(fmaxf(s[0], s[1]), fmaxf(s[2], s[3])));
                }
            }
        }
        #pragma unroll
        for (int it = 0; it < 4; ++it) {
            mA[it] = fmaxf(mA[it], __shfl_xor(mA[it], 16, 64));
            mA[it] = fmaxf(mA[it], __shfl_xor(mA[it], 32, 64));
        }
        if (q == 0) {
            #pragma unroll
            for (int it = 0; it < 4; ++it)
                stx[w][16 * it + i16] = mA[it];
        }
    }
    __syncthreads();

    float m2v[4];
    #pragma unroll
    for (int it = 0; it < 4; ++it) {
        int qrow = 16 * it + i16;
        m2v[it] = fmaxf(fmaxf(stx[0][qrow], stx[1][qrow]),
                        fmaxf(stx[2][qrow], stx[3][qrow]));
    }

    // ---- pass B: software-pipelined PV loop (round-3 verified) + inline l ----
    float4v O[2][4];
    #pragma unroll
    for (int ct = 0; ct < 2; ++ct)
        #pragma unroll
        for (int it = 0; it < 4; ++it)
            O[ct][it] = (float4v){0.f, 0.f, 0.f, 0.f};
    float lB[4] = {0.f, 0.f, 0.f, 0.f};

    const int jK = tid >> 2, dgK = tid & 3;      // K: 1 half8/thread
    const int cbV = tid >> 3, jgV = tid & 7;     // V: 4 half8/thread
    const int kaddr = jK * 32 + ((dgK ^ (jK & 3)) * 8);
    int vaddr[4];
    #pragma unroll
    for (int u = 0; u < 4; ++u) {
        int c = u * 32 + cbV;
        vaddr[u] = c * 64 + ((jgV ^ (c & 7)) * 8);
    }

    half8 kv, vv[4];
    kv = *(const half8*)(Ktb + (size_t)jK * DQ + 8 * dgK);
    #pragma unroll
    for (int u = 0; u < 4; ++u)
        vv[u] = *(const half8*)(Vb + (size_t)(u * 32 + cbV) * NN + 8 * jgV);
    *(half8*)&k_lds[0][kaddr] = kv;
    #pragma unroll
    for (int u = 0; u < 4; ++u)
        *(half8*)&v_lds[0][vaddr[u]] = vv[u];
    kv = *(const half8*)(Ktb + (size_t)(64 + jK) * DQ + 8 * dgK);
    #pragma unroll
    for (int u = 0; u < 4; ++u)
        vv[u] = *(const half8*)(Vb + (size_t)(u * 32 + cbV) * NN + 64 + 8 * jgV);

    for (int t = 0; t <= 64; ++t) {
        __syncthreads();
        // stage tile t+1 from regs (loaded at iter t-1)
        if (t < 63) {
            *(half8*)&k_lds[(t + 1) & 1][kaddr] = kv;
            const int vn = (t + 1) % 3;
            #pragma unroll
            for (int u = 0; u < 4; ++u)
                *(half8*)&v_lds[vn][vaddr[u]] = vv[u];
        }
        // issue prefetch of tile t+2 (drained by next barrier; covers S+PV)
        if (t < 62) {
            int jn = (t + 2) * 64;
            kv = *(const half8*)(Ktb + (size_t)(jn + jK) * DQ + 8 * dgK);
            #pragma unroll
            for (int u = 0; u < 4; ++u)
                vv[u] = *(const half8*)(Vb + (size_t)(u * 32 + cbV) * NN + jn + 8 * jgV);
        }
        // PV(t-1): inputs were completed before this iter's barrier
        if (t > 0) {
            const _Float16* psp = ps[(t - 1) & 1];
            const _Float16* vp  = v_lds[(t - 1) % 3];
            half8 pb[2][4];
            #pragma unroll
            for (int ks = 0; ks < 2; ++ks)
                #pragma unroll
                for (int it = 0; it < 4; ++it)
                    pb[ks][it] = *(const half8*)&psp[(16 * it + i16) * 72 + 32 * ks + 8 * q];
            __builtin_amdgcn_s_setprio(1);
            #pragma unroll
            for (int ct = 0; ct < 2; ++ct) {
                int c = 32 * w + 16 * ct + i16;
                #pragma unroll
                for (int ks = 0; ks < 2; ++ks) {
                    int g = 4 * ks + q;
                    half8 va = *(const half8*)&vp[c * 64 + ((g ^ (c & 7)) * 8)];
                    #pragma unroll
                    for (int it = 0; it < 4; ++it)
                        O[ct][it] = __builtin_amdgcn_mfma_f32_16x16x32_f16(va, pb[ks][it], O[ct][it], 0, 0, 0);
                }
            }
            __builtin_amdgcn_s_setprio(0);
        }
        // S(t) -> ps[t&1]; accumulate l from the f32 P' values
        if (t < 64) {
            int j = 16 * w + i16;
            half8 ka = *(const half8*)&k_lds[t & 1][j * 32 + ((q ^ (j & 3)) * 8)];
            _Float16* psc = ps[t & 1];
            #pragma unroll
            for (int it = 0; it < 4; ++it) {
                float4v z = {0.f, 0.f, 0.f, 0.f};
                float4v s = __builtin_amdgcn_mfma_f32_16x16x32_f16(ka, qb[it], z, 0, 0, 0);
                float p0 = exp2f(s[0] - m2v[it]);
                float p1 = exp2f(s[1] - m2v[it]);
                float p2 = exp2f(s[2] - m2v[it]);
                float p3 = exp2f(s[3] - m2v[it]);
                lB[it] += (p0 + p1) + (p2 + p3);
                half4 hv = { (_Float16)p0, (_Float16)p1, (_Float16)p2, (_Float16)p3 };
                *(half4*)&psc[(16 * it + i16) * 72 + 16 * w + 4 * q] = hv;
            }
        }
    }

    // reduce l: over q-quads (keys 4q+r), then across waves (key strips)
    #pragma unroll
    for (int it = 0; it < 4; ++it) {
        lB[it] += __shfl_xor(lB[it], 16, 64);
        lB[it] += __shfl_xor(lB[it], 32, 64);
    }
    if (q == 0) {
        #pragma unroll
        for (int it = 0; it < 4; ++it)
            stx[w][16 * it + i16] = lB[it];
    }
    __syncthreads();
    float linv[4];
    #pragma unroll
    for (int it = 0; it < 4; ++it) {
        int qrow = 16 * it + i16;
        linv[it] = 1.0f / ((stx[0][qrow] + stx[1][qrow]) + (stx[2][qrow] + stx[3][qrow]));
    }

    // epilogue: O * (1/l) + residual
    const float* xb = x + (size_t)b * CC * NN;
    float* ob = out + (size_t)b * CC * NN;
    #pragma unroll
    for (int ct = 0; ct < 2; ++ct)
        #pragma unroll
        for (int it = 0; it < 4; ++it)
            #pragma unroll
            for (int r = 0; r < 4; ++r) {
                int c = c0 + 32 * w + 16 * ct + 4 * q + r;
                size_t idx = (size_t)c * NN + i0 + 16 * it + i16;
                ob[idx] = xb[idx] + O[ct][it][r] * linv[it];
            }
}

extern "C" void kernel_launch(void* const* d_in, const int* in_sizes, int n_in,
                              void* d_out, int out_size, void* d_ws, size_t ws_size,
                              hipStream_t stream) {
    const float* x  = (const float*)d_in[0];
    const float* Wq = (const float*)d_in[1];
    const float* bq = (const float*)d_in[2];
    const float* Wk = (const float*)d_in[3];
    const float* bk = (const float*)d_in[4];
    const float* Wv = (const float*)d_in[5];
    const float* bv = (const float*)d_in[6];
    float* out = (float*)d_out;

    char* ws = (char*)d_ws;
    _Float16* Wh = (_Float16*)(ws);                 // 320*256*2 = 163840
    float*    bh = (float*)(ws + 163840);           // 1280
    _Float16* Qt = (_Float16*)(ws + 262144);        // 4*4096*32*2 = 1 MB
    _Float16* Kt = (_Float16*)(ws + 1310720);       // 1 MB
    _Float16* Vh = (_Float16*)(ws + 2359296);       // 4*256*4096*2 = 8 MB

    prep_kernel<<<dim3(320), 64, 0, stream>>>(Wq, bq, Wk, bk, Wv, bv, Wh, bh);
    proj_kernel<<<dim3(NN / 32, BB), 256, 0, stream>>>(x, Wh, bh, Qt, Kt, Vh);
    attn_kernel<<<dim3(NN / 64, 2, BB), 256, 0, stream>>>(x, Qt, Kt, Vh, out);
}